// Round 1
// baseline (231.382 us; speedup 1.0000x reference)
//
#include <hip/hip_runtime.h>
#include <hip/hip_bf16.h>

// ---------------------------------------------------------------------------
// Swin shifted-window attention, fully fused per-window kernel.
//   x:[8,128,128,256] f32, w_qkv:[256,768], pos:[15,15], w_out:[256,256], b_out:[256]
//   out:[8,128,128,256] f32
// One block = one (batch, wy, wx) window; 512 threads = 8 waves = 8 heads.
// All matmuls via v_mfma_f32_32x32x16_bf16, fp32 accumulate.
//
// MFMA 32x32x16 layouts used throughout (guide §3, m74/m101 verified):
//   A-frag: lane l supplies A[m = l%32][k = 8*(l>>5)+i], i=0..7 (8 bf16 = 16B)
//   B-frag: lane l supplies B[k = 8*(l>>5)+i][n = l%32]
//   C/D   : element (row,col): col = l&31, row = (reg&3) + 8*(reg>>2) + 4*(l>>5)
// ---------------------------------------------------------------------------

typedef __attribute__((ext_vector_type(8)))  short bf16x8;
typedef __attribute__((ext_vector_type(16))) float f32x16;

#define MFMA32(a, b, c) __builtin_amdgcn_mfma_f32_32x32x16_bf16((a), (b), (c), 0, 0, 0)

#define QK_SCALE 0.17677669529663687f  // 1/sqrt(32)
#define LOG2E    1.44269504088896340f

__device__ __forceinline__ uint32_t pack2(float lo, float hi) {
  uint32_t l = (uint32_t)__bfloat16_as_ushort(__float2bfloat16(lo));
  uint32_t h = (uint32_t)__bfloat16_as_ushort(__float2bfloat16(hi));
  return l | (h << 16);
}

__device__ __forceinline__ bf16x8 frag_from_u4(uint32_t a, uint32_t b,
                                               uint32_t c, uint32_t d) {
  union { uint32_t u[4]; bf16x8 v; } r;
  r.u[0] = a; r.u[1] = b; r.u[2] = c; r.u[3] = d;
  return r.v;
}

// Assemble an MFMA A/B fragment whose k-dim walks the ROW index of a 32x32
// accumulator M (acc element: row=(reg&3)+8*(reg>>2)+4*hf, col=lane&31) and
// whose m/n index equals col (= lane&31).  Fragment k = 16*kt + 8*hf + i.
// Own lane holds rows with bit2(row)==hf; partner (lane^32, same col) holds
// the complement -> 4 packs + 4 shfl_xor(32) + 4 selects.
__device__ __forceinline__ bf16x8 makefrag(const f32x16& a, int kt, int hf) {
  const int b0 = kt * 8;
  uint32_t q0 = pack2(a[b0 + 0], a[b0 + 1]);
  uint32_t q1 = pack2(a[b0 + 2], a[b0 + 3]);
  uint32_t q2 = pack2(a[b0 + 4], a[b0 + 5]);
  uint32_t q3 = pack2(a[b0 + 6], a[b0 + 7]);
  uint32_t x0 = (uint32_t)__shfl_xor((int)q0, 32, 64);
  uint32_t x1 = (uint32_t)__shfl_xor((int)q1, 32, 64);
  uint32_t x2 = (uint32_t)__shfl_xor((int)q2, 32, 64);
  uint32_t x3 = (uint32_t)__shfl_xor((int)q3, 32, 64);
  uint32_t d0 = hf ? x2 : q0;
  uint32_t d1 = hf ? x3 : q1;
  uint32_t d2 = hf ? q2 : x0;
  uint32_t d3 = hf ? q3 : x1;
  return frag_from_u4(d0, d1, d2, d3);
}

// ---------------------------------------------------------------------------
// Prep: w_qkv [256][768] -> WT bf16 [768][256] (row n = output col, contig k),
//       q-section (n<256) pre-scaled by 1/sqrt(hd);
//       w_out [256][256] -> WoT bf16 [256][256] transposed.
// ---------------------------------------------------------------------------
__global__ void prep_weights(const float* __restrict__ wqkv,
                             const float* __restrict__ wout,
                             ushort* __restrict__ WT,
                             ushort* __restrict__ WoT) {
  int id = blockIdx.x * 256 + threadIdx.x;
  if (id < 196608) {                       // 768*256
    int n = id >> 8, k = id & 255;
    float v = wqkv[k * 768 + n];
    if (n < 256) v *= QK_SCALE;            // fold QK scale into Wq
    WT[id] = __bfloat16_as_ushort(__float2bfloat16(v));
  } else if (id < 262144) {                // + 256*256
    int j = id - 196608;
    int n = j >> 8, k = j & 255;
    WoT[j] = __bfloat16_as_ushort(__float2bfloat16(wout[k * 256 + n]));
  }
}

// ---------------------------------------------------------------------------
__global__ __launch_bounds__(512, 2) void swin_attn(
    const float* __restrict__ x, const float* __restrict__ pos,
    const float* __restrict__ bout, const ushort* __restrict__ WT,
    const ushort* __restrict__ WoT, float* __restrict__ out) {
  // LDS: x window as bf16, k-grouped: slot(kg,tok) = 16B of k=8kg..8kg+7 for
  // token tok; swizzled slot ^= (kg>>2) so staging writes are conflict-free.
  __shared__ uint4  ldsX[32 * 64];         // 32 KB
  __shared__ ushort ldsO[32 * 64 * 8];     // 32 KB, O^T bf16 same k-grouping

  const int bid = blockIdx.x;
  const int b  = bid >> 8;
  const int wy = (bid >> 4) & 15;
  const int wx = bid & 15;
  const int t    = threadIdx.x;
  const int lane = t & 63;
  const int h    = t >> 6;                 // wave id == head id
  const int l31  = lane & 31;
  const int hf   = lane >> 5;

  f32x16 zf;
  #pragma unroll
  for (int i = 0; i < 16; ++i) zf[i] = 0.0f;

  // ---- stage shifted x window -> LDS bf16 -------------------------------
  {
    int tok = t >> 3, kc = t & 7;
    int ty = tok >> 3, tx = tok & 7;
    int yy = (wy * 8 + ty + 4) & 127;      // roll(-4,-4) folded into read
    int xx = (wx * 8 + tx + 4) & 127;
    const float* xr = x + (((b * 128 + yy) * 128 + xx) << 8) + kc * 32;
    #pragma unroll
    for (int g = 0; g < 4; ++g) {
      float4 a = *(const float4*)(xr + g * 8);
      float4 c = *(const float4*)(xr + g * 8 + 4);
      uint4 w;
      w.x = pack2(a.x, a.y); w.y = pack2(a.z, a.w);
      w.z = pack2(c.x, c.y); w.w = pack2(c.z, c.w);
      int kg = kc * 4 + g;
      ldsX[(kg * 64 + tok) ^ kc] = w;      // kc == kg>>2
    }
  }
  __syncthreads();

  // ---- phase 1: QKV.  qt/kt accs hold Q^T,K^T (row=d, col=token);
  //      vv holds V (row=token, col=d). Same x-frag feeds all three.
  const ushort* wq = WT + (h * 32 + l31) * 256;
  const ushort* wk = wq + 65536;
  const ushort* wv = wk + 65536;
  f32x16 qt[2], kv[2], vv[2];
  qt[0] = zf; qt[1] = zf; kv[0] = zf; kv[1] = zf; vv[0] = zf; vv[1] = zf;

  #pragma unroll
  for (int kt = 0; kt < 16; ++kt) {
    int k0 = kt * 16 + hf * 8;
    int kg = 2 * kt + hf;
    uint4 ux0 = ldsX[(kg * 64 + l31) ^ (kg >> 2)];
    uint4 ux1 = ldsX[(kg * 64 + 32 + l31) ^ (kg >> 2)];
    bf16x8 xf0 = frag_from_u4(ux0.x, ux0.y, ux0.z, ux0.w);
    bf16x8 xf1 = frag_from_u4(ux1.x, ux1.y, ux1.z, ux1.w);
    bf16x8 fq = *(const bf16x8*)(wq + k0);
    bf16x8 fk = *(const bf16x8*)(wk + k0);
    bf16x8 fv = *(const bf16x8*)(wv + k0);
    qt[0] = MFMA32(fq, xf0, qt[0]);  qt[1] = MFMA32(fq, xf1, qt[1]);
    kv[0] = MFMA32(fk, xf0, kv[0]);  kv[1] = MFMA32(fk, xf1, kv[1]);
    vv[0] = MFMA32(xf0, fv, vv[0]);  vv[1] = MFMA32(xf1, fv, vv[1]);
  }

  // ---- phase 2: S^T = K · Q^T  (s[ai][bi]: row n = key tok, col m = query tok)
  f32x16 s[2][2];
  s[0][0] = zf; s[0][1] = zf; s[1][0] = zf; s[1][1] = zf;
  #pragma unroll
  for (int kt = 0; kt < 2; ++kt) {
    bf16x8 aK0 = makefrag(kv[0], kt, hf);
    bf16x8 aK1 = makefrag(kv[1], kt, hf);
    bf16x8 bQ0 = makefrag(qt[0], kt, hf);
    bf16x8 bQ1 = makefrag(qt[1], kt, hf);
    s[0][0] = MFMA32(aK0, bQ0, s[0][0]);
    s[0][1] = MFMA32(aK0, bQ1, s[0][1]);
    s[1][0] = MFMA32(aK1, bQ0, s[1][0]);
    s[1][1] = MFMA32(aK1, bQ1, s[1][1]);
  }

  // ---- bias + shifted-window mask (dots[m][n], here at S^T element (n,m))
  const int maskUL = (wy == 15);
  const int maskLR = (wx == 15);
  #pragma unroll
  for (int ai = 0; ai < 2; ++ai)
    #pragma unroll
    for (int bi = 0; bi < 2; ++bi)
      #pragma unroll
      for (int r = 0; r < 16; ++r) {
        int n = (r & 3) + 8 * (r >> 2) + 4 * hf + 32 * ai;   // key token
        int m = l31 + 32 * bi;                               // query token
        float v = s[ai][bi][r] +
                  pos[((n >> 3) - (m >> 3) + 7) * 15 + ((n & 7) - (m & 7) + 7)];
        if ((maskUL && ((m >= 32) != (n >= 32))) ||
            (maskLR && (((m & 7) >= 4) != ((n & 7) >= 4))))
          v = -1e30f;
        s[ai][bi][r] = v;
      }

  // ---- softmax over n (rows of S^T): local reduce + one shfl_xor(32)
  #pragma unroll
  for (int bi = 0; bi < 2; ++bi) {
    float mx = -3e38f;
    #pragma unroll
    for (int ai = 0; ai < 2; ++ai)
      #pragma unroll
      for (int r = 0; r < 16; ++r) mx = fmaxf(mx, s[ai][bi][r]);
    mx = fmaxf(mx, __shfl_xor(mx, 32, 64));
    float sum = 0.0f;
    #pragma unroll
    for (int ai = 0; ai < 2; ++ai)
      #pragma unroll
      for (int r = 0; r < 16; ++r) {
        float p = exp2f((s[ai][bi][r] - mx) * LOG2E);
        s[ai][bi][r] = p;
        sum += p;
      }
    sum += __shfl_xor(sum, 32, 64);
    float ri = 1.0f / sum;
    #pragma unroll
    for (int ai = 0; ai < 2; ++ai)
      #pragma unroll
      for (int r = 0; r < 16; ++r) s[ai][bi][r] *= ri;
  }

  // ---- phase 3: O = P · V  (o[mt]: row=token, col=d) -------------------
  f32x16 o[2];
  o[0] = zf; o[1] = zf;
  #pragma unroll
  for (int kt = 0; kt < 4; ++kt) {
    bf16x8 bV  = makefrag(vv[kt >> 1], kt & 1, hf);
    bf16x8 aP0 = makefrag(s[kt >> 1][0], kt & 1, hf);
    bf16x8 aP1 = makefrag(s[kt >> 1][1], kt & 1, hf);
    o[0] = MFMA32(aP0, bV, o[0]);
    o[1] = MFMA32(aP1, bV, o[1]);
  }

  // ---- O^T -> LDS bf16 (k = h*32 + d, same k-grouped layout) -----------
  {
    int kb = h * 32 + l31, kg = kb >> 3, k7 = kb & 7;
    #pragma unroll
    for (int mt = 0; mt < 2; ++mt)
      #pragma unroll
      for (int r = 0; r < 16; ++r) {
        int m = (r & 3) + 8 * (r >> 2) + 4 * hf + 32 * mt;
        ldsO[(kg * 64 + m) * 8 + k7] =
            __bfloat16_as_ushort(__float2bfloat16(mt ? o[1][r] : o[0][r]));
      }
  }
  __syncthreads();

  // ---- phase 4: out^T = W_out^T · O^T  (wave h -> out cols h*32..h*32+31)
  const ushort* wo = WoT + (h * 32 + l31) * 256;
  f32x16 u[2];
  u[0] = zf; u[1] = zf;
  #pragma unroll
  for (int kt = 0; kt < 16; ++kt) {
    int k0 = kt * 16 + hf * 8;
    int kg = 2 * kt + hf;
    bf16x8 wa = *(const bf16x8*)(wo + k0);
    bf16x8 b0 = *(const bf16x8*)&ldsO[(kg * 64 + l31) * 8];
    bf16x8 b1 = *(const bf16x8*)&ldsO[(kg * 64 + 32 + l31) * 8];
    u[0] = MFMA32(wa, b0, u[0]);
    u[1] = MFMA32(wa, b1, u[1]);
  }

  // ---- epilogue: + b_out, write fp32 with roll(+4,+4) folded in --------
  #pragma unroll
  for (int tt = 0; tt < 2; ++tt) {
    int tok = 32 * tt + l31;
    int ty = tok >> 3, tx = tok & 7;
    int yy = (wy * 8 + ty + 4) & 127;
    int xx = (wx * 8 + tx + 4) & 127;
    float* ob = out + (((b * 128 + yy) * 128 + xx) << 8);
    #pragma unroll
    for (int g = 0; g < 4; ++g) {
      int c0 = h * 32 + 8 * g + 4 * hf;
      float4 bo = *(const float4*)(bout + c0);
      float4 v;
      v.x = (tt ? u[1][4 * g + 0] : u[0][4 * g + 0]) + bo.x;
      v.y = (tt ? u[1][4 * g + 1] : u[0][4 * g + 1]) + bo.y;
      v.z = (tt ? u[1][4 * g + 2] : u[0][4 * g + 2]) + bo.z;
      v.w = (tt ? u[1][4 * g + 3] : u[0][4 * g + 3]) + bo.w;
      *(float4*)(ob + c0) = v;
    }
  }
}

// ---------------------------------------------------------------------------
extern "C" void kernel_launch(void* const* d_in, const int* in_sizes, int n_in,
                              void* d_out, int out_size, void* d_ws, size_t ws_size,
                              hipStream_t stream) {
  const float* x    = (const float*)d_in[0];
  const float* wqkv = (const float*)d_in[1];
  const float* pos  = (const float*)d_in[2];
  const float* wout = (const float*)d_in[3];
  const float* bout = (const float*)d_in[4];

  ushort* WT  = (ushort*)d_ws;       // [768][256] bf16
  ushort* WoT = WT + 768 * 256;      // [256][256] bf16

  prep_weights<<<1024, 256, 0, stream>>>(wqkv, wout, WT, WoT);
  swin_attn<<<2048, 512, 0, stream>>>(x, pos, bout, WT, WoT, (float*)d_out);
}